// Round 13
// baseline (170.141 us; speedup 1.0000x reference)
//
#include <hip/hip_runtime.h>

typedef __attribute__((ext_vector_type(4))) float f32x4;

#define NT 256
#define S 10
#define D 100
#define H 16
#define NITER 5
#define LPR 4               // lanes cooperating on one batch row
#define RPB (NT / LPR)      // 64 batch rows per block
#define RQ 25               // out-staging row stride in quads (24 used + 1 pad)
#define OUTQ 24             // quads per output row (6*16 floats)

// Wave-uniform weight/bias reads straight from global (scalar/constant
// cache path; no LDS tile -> no VGPR promotion balloon -> no spill).
#define WQ(base, d, q) (*(const f32x4*)&(base)[(d) * H + (q) * 4])

__global__ __launch_bounds__(NT, 1)
void attn_greedy_kernel(const float* __restrict__ user_intent,
                        const float* __restrict__ item_corpus,
                        const float* __restrict__ W_proj,
                        const float* __restrict__ b_proj,
                        const float* __restrict__ W_k,
                        const float* __restrict__ b_k,
                        float* __restrict__ out)
{
    __shared__ f32x4 s_out[RPB * RQ];      // 25.6 KB out staging (only LDS)

    const int t = threadIdx.x;
    const int quarter = t & 3;             // lane within the 4-lane row group
    const int r = t >> 2;                  // batch row within block
    const size_t b = (size_t)blockIdx.x * RPB + r;
    // rows per lane: {3,3,2,2}; global s start: {0,3,6,8}
    const bool has3 = (quarter < 2);
    const int sbase = has3 ? quarter * 3 : 2 + quarter * 2;

    const f32x4* crow = (const f32x4*)item_corpus + b * (S * D / 4) + sbase * (D / 4);
    // third-row offset clamped in-bounds for !has3 lanes (its result is
    // computed but never consumed: all downstream uses are guarded).
    const int ls2off = has3 ? 2 * (D / 4) : 1 * (D / 4);

    // biases: uniform -> scalar regs
    f32x4 bp[4], bk[4];
    #pragma unroll
    for (int q = 0; q < 4; ++q) {
        bp[q] = *(const f32x4*)&b_proj[q * 4];
        bk[q] = *(const f32x4*)&b_k[q * 4];
    }

    // user_intent: all 4 lanes hold the row (same cache line; broadcast).
    const f32x4* urow = (const f32x4*)user_intent + b * 4;
    f32x4 usum[4];
    #pragma unroll
    for (int q = 0; q < 4; ++q) {
        usum[q] = urow[q];
        if (quarter == 0) s_out[r * RQ + q] = usum[q];   // ui[:,0,:]
    }

    // ---- Projection, INTERCHANGED: i outer, rows inner. Each W_proj quad
    // loaded ONCE per thread (400 total, was 1200) and reused for all 3
    // rows; 3 independent corpus loads in flight per step (3x memory ILP).
    // Per-(row,h) accumulation order still d-ascending -> bit-identical.
    f32x4 ic[3][4];
    #pragma unroll
    for (int ls = 0; ls < 3; ++ls)
        #pragma unroll
        for (int q = 0; q < 4; ++q) ic[ls][q] = bp[q];

    #pragma unroll 5
    for (int i = 0; i < D / 4; ++i) {
        f32x4 c0 = crow[i];
        f32x4 c1 = crow[(D / 4) + i];
        f32x4 c2 = crow[ls2off + i];
        #pragma unroll
        for (int dd = 0; dd < 4; ++dd) {
            const int d = i * 4 + dd;
            f32x4 w0 = WQ(W_proj, d, 0);
            f32x4 w1 = WQ(W_proj, d, 1);
            f32x4 w2 = WQ(W_proj, d, 2);
            f32x4 w3 = WQ(W_proj, d, 3);
            float a0 = c0[dd], a1 = c1[dd], a2 = c2[dd];
            ic[0][0] += a0 * w0; ic[0][1] += a0 * w1;
            ic[0][2] += a0 * w2; ic[0][3] += a0 * w3;
            ic[1][0] += a1 * w0; ic[1][1] += a1 * w1;
            ic[1][2] += a1 * w2; ic[1][3] += a1 * w3;
            ic[2][0] += a2 * w0; ic[2][1] += a2 * w1;
            ic[2][2] += a2 * w2; ic[2][3] += a2 * w3;
        }
    }

    // ---- Greedy iterations: exactly r11's verified phase (in-place per-row
    // matvec keeps peak VGPR low; guards keep !has3 lanes' ic[2] inert).
    #pragma unroll 1
    for (int it = 0; it < NITER; ++it) {
        #pragma unroll
        for (int ls = 0; ls < 3; ++ls) {
            if (ls < 2 || has3) {
                f32x4 n0 = bk[0], n1 = bk[1], n2 = bk[2], n3 = bk[3];
                #pragma unroll
                for (int k = 0; k < H; ++k) {
                    float a = ic[ls][k >> 2][k & 3];
                    n0 += a * WQ(W_k, k, 0);
                    n1 += a * WQ(W_k, k, 1);
                    n2 += a * WQ(W_k, k, 2);
                    n3 += a * WQ(W_k, k, 3);
                }
                ic[ls][0] = n0; ic[ls][1] = n1; ic[ls][2] = n2; ic[ls][3] = n3;
            }
        }

        // src = mean(ui); usum bit-identical in all 4 lanes
        float cnt = (float)(it + 1);
        f32x4 src[4];
        #pragma unroll
        for (int q = 0; q < 4; ++q) src[q] = usum[q] / cnt;

        // local scores + first-max argmax (global s index), guarded
        float best = -__builtin_inff();
        int gidx = sbase;
        #pragma unroll
        for (int ls = 0; ls < 3; ++ls) {
            if (ls < 2 || has3) {
                float sc = 0.0f;
                #pragma unroll
                for (int q = 0; q < 4; ++q)
                    #pragma unroll
                    for (int c = 0; c < 4; ++c)
                        sc += ic[ls][q][c] * src[q][c];
                if (sc > best) { best = sc; gidx = sbase + ls; }
            }
        }

        // lexicographic (score, -idx) over the 4-lane group == first-max
        #pragma unroll
        for (int off = 1; off <= 2; off <<= 1) {
            float osc = __shfl_xor(best, off);
            int oidx = __shfl_xor(gidx, off);
            if (osc > best || (osc == best && oidx < gidx)) { best = osc; gidx = oidx; }
        }

        // item_vec broadcast: owner selects, others 0, xor-sum (x+0+0+0 exact)
        f32x4 iv[4];
        #pragma unroll
        for (int q = 0; q < 4; ++q) iv[q] = f32x4{0.f, 0.f, 0.f, 0.f};
        #pragma unroll
        for (int ls = 0; ls < 3; ++ls) {
            if (ls < 2 || has3) {
                bool take = ((sbase + ls) == gidx);
                #pragma unroll
                for (int q = 0; q < 4; ++q)
                    iv[q] = take ? ic[ls][q] : iv[q];
            }
        }
        #pragma unroll
        for (int off = 1; off <= 2; off <<= 1)
            #pragma unroll
            for (int q = 0; q < 4; ++q)
                #pragma unroll
                for (int c = 0; c < 4; ++c)
                    iv[q][c] += __shfl_xor(iv[q][c], off);

        #pragma unroll
        for (int q = 0; q < 4; ++q) {
            usum[q] += iv[q];
            if (quarter == 0) s_out[r * RQ + (it + 1) * 4 + q] = iv[q];
        }
    }

    // ---- Coalesced output: 64 rows x 24 quads = contiguous 24 KB per block.
    __syncthreads();
    f32x4* out4 = (f32x4*)out;
    const size_t obase = (size_t)blockIdx.x * RPB * OUTQ;
    #pragma unroll
    for (int k = 0; k < (RPB * OUTQ) / NT; ++k) {   // 6 iterations
        int j = t + k * NT;
        int row = j / OUTQ;
        int q = j - row * OUTQ;
        out4[obase + j] = s_out[row * RQ + q];
    }
}

extern "C" void kernel_launch(void* const* d_in, const int* in_sizes, int n_in,
                              void* d_out, int out_size, void* d_ws, size_t ws_size,
                              hipStream_t stream) {
    const float* user_intent = (const float*)d_in[0];
    const float* item_corpus = (const float*)d_in[1];
    const float* W_proj      = (const float*)d_in[2];
    const float* b_proj      = (const float*)d_in[3];
    const float* W_k         = (const float*)d_in[4];
    const float* b_k         = (const float*)d_in[5];
    float* out = (float*)d_out;

    const int bs = 65536;
    hipLaunchKernelGGL(attn_greedy_kernel,
                       dim3(bs / RPB), dim3(NT), 0, stream,
                       user_intent, item_corpus, W_proj, b_proj, W_k, b_k, out);
}

// Round 14
// 120.802 us; speedup vs baseline: 1.4084x; 1.4084x over previous
//
#include <hip/hip_runtime.h>

typedef __attribute__((ext_vector_type(4))) float f32x4;

#define NT 256
#define S 10
#define D 100
#define H 16
#define NITER 5
#define LPR 8               // lanes cooperating on one batch row
#define RPB (NT / LPR)      // 32 batch rows per block
#define RQ 25               // out-staging row stride in quads (24 used + 1 pad)
#define OUTQ 24             // quads per output row (6*16 floats)

// Wave-uniform weight/bias reads straight from global (scalar/constant
// cache path; no LDS tile -> no VGPR promotion balloon -> no spill).
#define WQ(base, d, q) (*(const f32x4*)&(base)[(d) * H + (q) * 4])

__global__ __launch_bounds__(NT, 1)
void attn_greedy_kernel(const float* __restrict__ user_intent,
                        const float* __restrict__ item_corpus,
                        const float* __restrict__ W_proj,
                        const float* __restrict__ b_proj,
                        const float* __restrict__ W_k,
                        const float* __restrict__ b_k,
                        float* __restrict__ out)
{
    __shared__ f32x4 s_out[RPB * RQ];      // 12.8 KB out staging (only LDS)

    const int t = threadIdx.x;
    const int oct = t & 7;                 // lane within the 8-lane row group
    const int r = t >> 3;                  // batch row within block
    const size_t b = (size_t)blockIdx.x * RPB + r;
    // rows per lane: {2,2,1,1,1,1,1,1}; global s start: {0,2,4,5,6,7,8,9}
    const bool has2 = (oct < 2);
    const int sbase = has2 ? oct * 2 : 2 + oct;

    const f32x4* crow = (const f32x4*)item_corpus + b * (S * D / 4) + sbase * (D / 4);

    // biases: uniform -> scalar regs
    f32x4 bp[4], bk[4];
    #pragma unroll
    for (int q = 0; q < 4; ++q) {
        bp[q] = *(const f32x4*)&b_proj[q * 4];
        bk[q] = *(const f32x4*)&b_k[q * 4];
    }

    // user_intent: all 8 lanes hold the row (same cache line; broadcast).
    const f32x4* urow = (const f32x4*)user_intent + b * 4;
    f32x4 usum[4];
    #pragma unroll
    for (int q = 0; q < 4; ++q) {
        usum[q] = urow[q];
        if (oct == 0) s_out[r * RQ + q] = usum[q];   // ui[:,0,:]
    }

    // ---- Projection of this lane's 1-2 rows, s OUTER / i INNER: ONE live
    // corpus stream per lane (r13 lesson: >1 stream/lane thrashes L1 and
    // re-fetches 1.8x). d-ascending accumulation -> bit-identical.
    f32x4 ic[2][4];
    #pragma unroll
    for (int ls = 0; ls < 2; ++ls) {
        if (ls == 0 || has2) {
            f32x4 a0 = bp[0], a1 = bp[1], a2 = bp[2], a3 = bp[3];
            #pragma unroll 5
            for (int i = 0; i < D / 4; ++i) {
                f32x4 c = crow[ls * (D / 4) + i];
                #pragma unroll
                for (int dd = 0; dd < 4; ++dd) {
                    float a = c[dd];
                    const int d = i * 4 + dd;
                    a0 += a * WQ(W_proj, d, 0);
                    a1 += a * WQ(W_proj, d, 1);
                    a2 += a * WQ(W_proj, d, 2);
                    a3 += a * WQ(W_proj, d, 3);
                }
            }
            ic[ls][0] = a0; ic[ls][1] = a1; ic[ls][2] = a2; ic[ls][3] = a3;
        }
    }

    // ---- Greedy iterations (r11's verified phase, guards adapted to 2 rows)
    #pragma unroll 1
    for (int it = 0; it < NITER; ++it) {
        // ic = ic @ Wk + bk, in place per local row (k ascending)
        #pragma unroll
        for (int ls = 0; ls < 2; ++ls) {
            if (ls == 0 || has2) {
                f32x4 n0 = bk[0], n1 = bk[1], n2 = bk[2], n3 = bk[3];
                #pragma unroll
                for (int k = 0; k < H; ++k) {
                    float a = ic[ls][k >> 2][k & 3];
                    n0 += a * WQ(W_k, k, 0);
                    n1 += a * WQ(W_k, k, 1);
                    n2 += a * WQ(W_k, k, 2);
                    n3 += a * WQ(W_k, k, 3);
                }
                ic[ls][0] = n0; ic[ls][1] = n1; ic[ls][2] = n2; ic[ls][3] = n3;
            }
        }

        // src = mean(ui); usum bit-identical in all 8 lanes
        float cnt = (float)(it + 1);
        f32x4 src[4];
        #pragma unroll
        for (int q = 0; q < 4; ++q) src[q] = usum[q] / cnt;

        // local scores + first-max argmax (global s index), guarded
        float best = -__builtin_inff();
        int gidx = sbase;
        #pragma unroll
        for (int ls = 0; ls < 2; ++ls) {
            if (ls == 0 || has2) {
                float sc = 0.0f;
                #pragma unroll
                for (int q = 0; q < 4; ++q)
                    #pragma unroll
                    for (int c = 0; c < 4; ++c)
                        sc += ic[ls][q][c] * src[q][c];
                if (sc > best) { best = sc; gidx = sbase + ls; }
            }
        }

        // lexicographic (score, -idx) over the 8-lane group == first-max
        // (each score computed exactly once -> exact)
        #pragma unroll
        for (int off = 1; off <= 4; off <<= 1) {
            float osc = __shfl_xor(best, off);
            int oidx = __shfl_xor(gidx, off);
            if (osc > best || (osc == best && oidx < gidx)) { best = osc; gidx = oidx; }
        }

        // item_vec broadcast: owner selects, others 0, xor-sum (x+0*7 exact)
        f32x4 iv[4];
        #pragma unroll
        for (int q = 0; q < 4; ++q) iv[q] = f32x4{0.f, 0.f, 0.f, 0.f};
        #pragma unroll
        for (int ls = 0; ls < 2; ++ls) {
            if (ls == 0 || has2) {
                bool take = ((sbase + ls) == gidx);
                #pragma unroll
                for (int q = 0; q < 4; ++q)
                    iv[q] = take ? ic[ls][q] : iv[q];
            }
        }
        #pragma unroll
        for (int off = 1; off <= 4; off <<= 1)
            #pragma unroll
            for (int q = 0; q < 4; ++q)
                #pragma unroll
                for (int c = 0; c < 4; ++c)
                    iv[q][c] += __shfl_xor(iv[q][c], off);

        #pragma unroll
        for (int q = 0; q < 4; ++q) {
            usum[q] += iv[q];
            if (oct == 0) s_out[r * RQ + (it + 1) * 4 + q] = iv[q];
        }
    }

    // ---- Coalesced output: 32 rows x 24 quads = contiguous 12 KB per block.
    __syncthreads();
    f32x4* out4 = (f32x4*)out;
    const size_t obase = (size_t)blockIdx.x * RPB * OUTQ;
    #pragma unroll
    for (int k = 0; k < (RPB * OUTQ) / NT; ++k) {   // 3 iterations
        int j = t + k * NT;
        int row = j / OUTQ;
        int q = j - row * OUTQ;
        out4[obase + j] = s_out[row * RQ + q];
    }
}

extern "C" void kernel_launch(void* const* d_in, const int* in_sizes, int n_in,
                              void* d_out, int out_size, void* d_ws, size_t ws_size,
                              hipStream_t stream) {
    const float* user_intent = (const float*)d_in[0];
    const float* item_corpus = (const float*)d_in[1];
    const float* W_proj      = (const float*)d_in[2];
    const float* b_proj      = (const float*)d_in[3];
    const float* W_k         = (const float*)d_in[4];
    const float* b_k         = (const float*)d_in[5];
    float* out = (float*)d_out;

    const int bs = 65536;
    hipLaunchKernelGGL(attn_greedy_kernel,
                       dim3(bs / RPB), dim3(NT), 0, stream,
                       user_intent, item_corpus, W_proj, b_proj, W_k, b_k, out);
}

// Round 15
// 114.998 us; speedup vs baseline: 1.4795x; 1.0505x over previous
//
#include <hip/hip_runtime.h>

typedef __attribute__((ext_vector_type(4))) float f32x4;

#define NT 256
#define S 10
#define D 100
#define H 16
#define NITER 5
#define GL 5                 // lanes per batch row: 2 s-rows each, NO waste
#define GPW 12               // groups per wave (lanes 0..59; 60..63 idle)
#define RPB (4 * GPW)        // 48 batch rows per 256-thread block
#define BS 65536
#define RQ 25                // out-staging row stride in quads (24 + 1 pad)
#define OUTQ 24              // quads per output row (6*16 floats)

// Wave-uniform weight/bias reads straight from global (scalar/constant
// cache path; no LDS tile -> no VGPR promotion balloon -> no spill).
#define WQ(base, d, q) (*(const f32x4*)&(base)[(d) * H + (q) * 4])

__global__ __launch_bounds__(NT, 1)
void attn_greedy_kernel(const float* __restrict__ user_intent,
                        const float* __restrict__ item_corpus,
                        const float* __restrict__ W_proj,
                        const float* __restrict__ b_proj,
                        const float* __restrict__ W_k,
                        const float* __restrict__ b_k,
                        float* __restrict__ out)
{
    __shared__ f32x4 s_out[RPB * RQ];      // 19.2 KB out staging (only LDS)

    const int t = threadIdx.x;
    const int lane = t & 63;
    const int wv = t >> 6;
    const int gl = lane % GL;              // 0..4: this lane's slot in group
    const int grp = lane / GL;             // 0..11 (12 for idle lanes)
    const bool valid = (lane < GL * GPW);  // lanes 60..63 idle (no stores)
    const int rr = valid ? (wv * GPW + grp) : 0;         // row within block
    const size_t b = (size_t)blockIdx.x * RPB + rr;
    const bool brow_ok = valid && (b < BS);
    const size_t bc = (b < BS) ? b : (BS - 1);           // clamp loads only

    // each lane owns s-rows {2*gl, 2*gl+1} -- uniform shape, no guards
    const f32x4* crow = (const f32x4*)item_corpus + bc * (S * D / 4)
                        + (gl * 2) * (D / 4);

    // biases: uniform -> scalar regs
    f32x4 bp[4], bk[4];
    #pragma unroll
    for (int q = 0; q < 4; ++q) {
        bp[q] = *(const f32x4*)&b_proj[q * 4];
        bk[q] = *(const f32x4*)&b_k[q * 4];
    }

    // user_intent: all group lanes hold the row (same line; broadcast).
    const f32x4* urow = (const f32x4*)user_intent + bc * 4;
    f32x4 usum[4];
    #pragma unroll
    for (int q = 0; q < 4; ++q) {
        usum[q] = urow[q];
        if (gl == 0 && brow_ok) s_out[rr * RQ + q] = usum[q];   // ui[:,0,:]
    }

    // ---- Projection of exactly 2 rows, s OUTER / i INNER: ONE live corpus
    // stream per lane (r13 lesson), d-ascending accumulation -> bit-identical.
    f32x4 ic[2][4];
    #pragma unroll
    for (int ls = 0; ls < 2; ++ls) {
        f32x4 a0 = bp[0], a1 = bp[1], a2 = bp[2], a3 = bp[3];
        #pragma unroll 5
        for (int i = 0; i < D / 4; ++i) {
            f32x4 c = crow[ls * (D / 4) + i];
            #pragma unroll
            for (int dd = 0; dd < 4; ++dd) {
                float a = c[dd];
                const int d = i * 4 + dd;
                a0 += a * WQ(W_proj, d, 0);
                a1 += a * WQ(W_proj, d, 1);
                a2 += a * WQ(W_proj, d, 2);
                a3 += a * WQ(W_proj, d, 3);
            }
        }
        ic[ls][0] = a0; ic[ls][1] = a1; ic[ls][2] = a2; ic[ls][3] = a3;
    }

    const int base = lane - gl;            // first lane of this group

    // ---- Greedy iterations (no divergence anywhere in the hot path)
    #pragma unroll 1
    for (int it = 0; it < NITER; ++it) {
        // ic = ic @ Wk + bk, in place per row (k ascending -> bit-identical)
        #pragma unroll
        for (int ls = 0; ls < 2; ++ls) {
            f32x4 n0 = bk[0], n1 = bk[1], n2 = bk[2], n3 = bk[3];
            #pragma unroll
            for (int k = 0; k < H; ++k) {
                float a = ic[ls][k >> 2][k & 3];
                n0 += a * WQ(W_k, k, 0);
                n1 += a * WQ(W_k, k, 1);
                n2 += a * WQ(W_k, k, 2);
                n3 += a * WQ(W_k, k, 3);
            }
            ic[ls][0] = n0; ic[ls][1] = n1; ic[ls][2] = n2; ic[ls][3] = n3;
        }

        // src = mean(ui); usum bit-identical within the group
        float cnt = (float)(it + 1);
        f32x4 src[4];
        #pragma unroll
        for (int q = 0; q < 4; ++q) src[q] = usum[q] / cnt;

        // local scores (q,c ascending) + local first-max over 2 rows
        float sc0 = 0.0f, sc1 = 0.0f;
        #pragma unroll
        for (int q = 0; q < 4; ++q)
            #pragma unroll
            for (int c = 0; c < 4; ++c) {
                sc0 += ic[0][q][c] * src[q][c];
                sc1 += ic[1][q][c] * src[q][c];
            }
        float best = sc0;
        int gidx = gl * 2;
        if (sc1 > best) { best = sc1; gidx = gl * 2 + 1; }

        // group fold, ascending lane order == ascending s: strict > keeps
        // the FIRST max -> exact np.argmax semantics. (Each score computed
        // exactly once, so equality compares identical bit patterns.)
        float fbest = __shfl(best, base & 63);
        int fidx = __shfl(gidx, base & 63);
        #pragma unroll
        for (int j = 1; j < GL; ++j) {
            float osc = __shfl(best, (base + j) & 63);
            int oidx = __shfl(gidx, (base + j) & 63);
            if (osc > fbest) { fbest = osc; fidx = oidx; }
        }

        // item_vec: pure broadcast from owner lane (bit-exact, no sums).
        // fidx is uniform in the group -> (fidx&1) select is non-divergent.
        const int owner = (base + (fidx >> 1)) & 63;
        f32x4 iv[4];
        #pragma unroll
        for (int q = 0; q < 4; ++q)
            #pragma unroll
            for (int c = 0; c < 4; ++c) {
                float cand = (fidx & 1) ? ic[1][q][c] : ic[0][q][c];
                iv[q][c] = __shfl(cand, owner);
            }

        #pragma unroll
        for (int q = 0; q < 4; ++q) {
            usum[q] += iv[q];
            if (gl == 0 && brow_ok) s_out[rr * RQ + (it + 1) * 4 + q] = iv[q];
        }
    }

    // ---- Coalesced output: 48 rows x 24 quads, contiguous per block.
    __syncthreads();
    f32x4* out4 = (f32x4*)out;
    const size_t rbase = (size_t)blockIdx.x * RPB;
    const size_t obase = rbase * OUTQ;
    #pragma unroll
    for (int k = 0; k < 5; ++k) {          // ceil(1152/256)
        int j = t + k * NT;
        if (j < RPB * OUTQ) {
            int row = j / OUTQ;
            int q = j - row * OUTQ;
            if (rbase + row < BS)
                out4[obase + j] = s_out[row * RQ + q];
        }
    }
}

extern "C" void kernel_launch(void* const* d_in, const int* in_sizes, int n_in,
                              void* d_out, int out_size, void* d_ws, size_t ws_size,
                              hipStream_t stream) {
    const float* user_intent = (const float*)d_in[0];
    const float* item_corpus = (const float*)d_in[1];
    const float* W_proj      = (const float*)d_in[2];
    const float* b_proj      = (const float*)d_in[3];
    const float* W_k         = (const float*)d_in[4];
    const float* b_k         = (const float*)d_in[5];
    float* out = (float*)d_out;

    const int nblocks = (BS + RPB - 1) / RPB;   // 1366
    hipLaunchKernelGGL(attn_greedy_kernel,
                       dim3(nblocks), dim3(NT), 0, stream,
                       user_intent, item_corpus, W_proj, b_proj, W_k, b_k, out);
}